// Round 1
// baseline (454.019 us; speedup 1.0000x reference)
//
#include <hip/hip_runtime.h>

// Edge_cycle fused block, bf16-MFMA, round 5.
//   Autobahn collapse: aut = linmap@[Wid;Wsum]+bab (linear, not an output) =>
//   y1 = relu(linmap @ Weff + beff), Weff = Wc1[0:128] + [Wid;Wsum]@Wc1[128:384].
//   All layers K=128. B-fragments are read DIRECTLY from global (L2-resident
//   128KB weight set) -- no LDS weight staging, no staging barriers.
//   Activations ping-pong bufA<->bufB: exactly one __syncthreads per layer.
//   Round 5: OPERAND-SWAP in the MFMA (mfma(B,A) computes (x@W)^T). A- and
//   B-fragments share the same register layout for 16x16x32, so the swap is
//   free; D then maps x_row=lane&15, n=(lane>>4)*4+r => each lane's 4 acc
//   values are 4 CONSECUTIVE columns of one row. LDS stores become packed
//   8B ds_write_b64 (was 4x scalar 2B), and the final global store becomes
//   one float4 (16B/lane, coalesced) instead of 4 scattered dwords.
// d_out layout: [edge_out NE*64][out5][out6]; cycle_out = d_out + NE*64.

#define LP 136   // LDS row pitch in bf16 units (128+8: 16B-aligned, 2-way-free banks)

typedef __attribute__((ext_vector_type(8))) short bhalf8;
typedef __attribute__((ext_vector_type(4))) float f32x4;

__device__ __forceinline__ unsigned short f2bf(float f) {
    unsigned u = __builtin_bit_cast(unsigned, f);
    u += 0x7fffu + ((u >> 16) & 1u);          // RNE
    return (unsigned short)(u >> 16);
}
__device__ __forceinline__ float bf2f(unsigned short s) {
    unsigned u = ((unsigned)s) << 16;
    return __builtin_bit_cast(float, u);
}
__device__ __forceinline__ void store4bf(unsigned short* p, float4 v) {
    uint2 u;
    u.x = (unsigned)f2bf(v.x) | ((unsigned)f2bf(v.y) << 16);
    u.y = (unsigned)f2bf(v.z) | ((unsigned)f2bf(v.w) << 16);
    *(uint2*)p = u;
}

// ---------------- prep kernels (2 launches total) -----------------------------
// blocks 0-63:W1  64-95:W2  96-159:Wc2  160-191:Wc3  192-255:We1  256-287:We2
__global__ void tcast_all(const float* __restrict__ W1,  const float* __restrict__ W2,
                          const float* __restrict__ Wc2, const float* __restrict__ Wc3,
                          const float* __restrict__ We1, const float* __restrict__ We2,
                          unsigned short* W1T, unsigned short* W2T,
                          unsigned short* Wc2T, unsigned short* Wc3T,
                          unsigned short* We1T, unsigned short* We2T) {
    int b = blockIdx.x;
    const float* W; unsigned short* WT; int logN, i0;
    if      (b < 64)  { W = W1;  WT = W1T;  logN = 7; i0 = b; }
    else if (b < 96)  { W = W2;  WT = W2T;  logN = 6; i0 = b - 64; }
    else if (b < 160) { W = Wc2; WT = Wc2T; logN = 7; i0 = b - 96; }
    else if (b < 192) { W = Wc3; WT = Wc3T; logN = 6; i0 = b - 160; }
    else if (b < 256) { W = We1; WT = We1T; logN = 7; i0 = b - 192; }
    else              { W = We2; WT = We2T; logN = 6; i0 = b - 256; }
    int i = i0 * 256 + threadIdx.x;
    int k = i >> logN;
    int n = i & ((1 << logN) - 1);
    WT[n * 128 + k] = f2bf(W[i]);
}

// blocks 0-127: WeffT5 row k=b; 128-255: WeffT6; 256: beff5; 257: beff6
__global__ void weff_all(const float* __restrict__ Wc1,
                         const float* __restrict__ Wid5, const float* __restrict__ Wsum5,
                         const float* __restrict__ Wid6, const float* __restrict__ Wsum6,
                         const float* __restrict__ bab5, const float* __restrict__ bab6,
                         const float* __restrict__ bc1,
                         unsigned short* WeffT5, unsigned short* WeffT6,
                         float* beff5, float* beff6) {
    int b = blockIdx.x, n = threadIdx.x;
    if (b < 256) {
        int k = b & 127;
        const float* Wid  = (b < 128) ? Wid5  : Wid6;
        const float* Wsum = (b < 128) ? Wsum5 : Wsum6;
        unsigned short* WT = (b < 128) ? WeffT5 : WeffT6;
        const float* Ws = (k < 64) ? (Wid + (size_t)k * 256) : (Wsum + (size_t)(k - 64) * 256);
        float v = Wc1[k * 128 + n];
        for (int j = 0; j < 256; ++j) v = fmaf(Ws[j], Wc1[(128 + j) * 128 + n], v);
        WT[n * 128 + k] = f2bf(v);
    } else {
        const float* bab = (b == 256) ? bab5 : bab6;
        float* beff = (b == 256) ? beff5 : beff6;
        float v = bc1[n];
        for (int j = 0; j < 256; ++j) v = fmaf(bab[j], Wc1[(128 + j) * 128 + n], v);
        beff[n] = v;
    }
}

// ---------------- MFMA layer: B direct from global, A from LDS ---------------
// Swapped-operand form: mfma(bfr, afr) = (x@W)^T fragment; lane holds
// x_row = m16, n = ntg*16 + q*4 + r  (r=0..3 contiguous cols -> packed store).
// G=2: N=128 (col groups w, w+4). G=1: N=64 (col group w).
template<int MT, bool RELU, int G>
__device__ __forceinline__ void layerG(const unsigned short* src, unsigned short* dst,
                                       const unsigned short* __restrict__ WT,
                                       const float* __restrict__ bias,
                                       int m16, int q, int w) {
    // B fragments straight from global (issued first to cover latency)
    bhalf8 bfr[G][4];
    #pragma unroll
    for (int g = 0; g < G; ++g) {
        const int ntg = w + g * 4;
        #pragma unroll
        for (int kc = 0; kc < 4; ++kc)
            bfr[g][kc] = *(const bhalf8*)&WT[(size_t)(ntg * 16 + m16) * 128 + kc * 32 + q * 8];
    }
    // A fragments from LDS
    bhalf8 afr[MT][4];
    #pragma unroll
    for (int mt = 0; mt < MT; ++mt)
        #pragma unroll
        for (int kc = 0; kc < 4; ++kc)
            afr[mt][kc] = *(const bhalf8*)&src[(mt * 16 + m16) * LP + kc * 32 + q * 8];
    #pragma unroll
    for (int g = 0; g < G; ++g) {
        const int ntg = w + g * 4;
        const float4 bb = *(const float4*)&bias[ntg * 16 + q * 4];
        #pragma unroll
        for (int mt = 0; mt < MT; ++mt) {
            f32x4 acc = {bb.x, bb.y, bb.z, bb.w};
            #pragma unroll
            for (int kc = 0; kc < 4; ++kc)
                acc = __builtin_amdgcn_mfma_f32_16x16x32_bf16(bfr[g][kc], afr[mt][kc], acc, 0, 0, 0);
            float v0 = acc[0], v1 = acc[1], v2 = acc[2], v3 = acc[3];
            if (RELU) {
                v0 = fmaxf(v0, 0.f); v1 = fmaxf(v1, 0.f);
                v2 = fmaxf(v2, 0.f); v3 = fmaxf(v3, 0.f);
            }
            uint2 u;
            u.x = (unsigned)f2bf(v0) | ((unsigned)f2bf(v1) << 16);
            u.y = (unsigned)f2bf(v2) | ((unsigned)f2bf(v3) << 16);
            *(uint2*)&dst[(mt * 16 + m16) * LP + ntg * 16 + q * 4] = u;
        }
    }
}

// N=64 final layer -> global fp32 (swapped: one float4 store per tile)
template<int MT>
__device__ __forceinline__ void layer_out(const unsigned short* src,
                                          const unsigned short* __restrict__ WT,
                                          const float* __restrict__ bias,
                                          float* __restrict__ out, int base,
                                          int m16, int q, int w) {
    bhalf8 bfr[4];
    #pragma unroll
    for (int kc = 0; kc < 4; ++kc)
        bfr[kc] = *(const bhalf8*)&WT[(size_t)(w * 16 + m16) * 128 + kc * 32 + q * 8];
    bhalf8 afr[MT][4];
    #pragma unroll
    for (int mt = 0; mt < MT; ++mt)
        #pragma unroll
        for (int kc = 0; kc < 4; ++kc)
            afr[mt][kc] = *(const bhalf8*)&src[(mt * 16 + m16) * LP + kc * 32 + q * 8];
    const float4 bb = *(const float4*)&bias[w * 16 + q * 4];
    #pragma unroll
    for (int mt = 0; mt < MT; ++mt) {
        f32x4 acc = {bb.x, bb.y, bb.z, bb.w};
        #pragma unroll
        for (int kc = 0; kc < 4; ++kc)
            acc = __builtin_amdgcn_mfma_f32_16x16x32_bf16(bfr[kc], afr[mt][kc], acc, 0, 0, 0);
        float4 o;
        o.x = acc[0]; o.y = acc[1]; o.z = acc[2]; o.w = acc[3];
        *(float4*)&out[(size_t)(base + mt * 16 + m16) * 64 + w * 16 + q * 4] = o;
    }
}

// ---------------- main kernels -----------------------------------------------
template<int S, int C, int MINW>
__global__ __launch_bounds__(256, MINW)
void cycle_mfma(const float* __restrict__ edge_rep, const float* __restrict__ cyc,
                const int* __restrict__ e2c,
                const unsigned short* __restrict__ W1T, const float* __restrict__ b1,
                const unsigned short* __restrict__ W2T, const float* __restrict__ b2,
                const unsigned short* __restrict__ WeffT, const float* __restrict__ beff,
                const unsigned short* __restrict__ Wc2T, const float* __restrict__ bc2,
                const unsigned short* __restrict__ Wc3T, const float* __restrict__ bc3,
                float* __restrict__ out) {
    constexpr int R = S * C;
    constexpr int MT = R / 16;
    static_assert(R % 16 == 0, "rows per block must be multiple of 16");
    __shared__ unsigned short bufA[R * LP];
    __shared__ unsigned short bufB[R * LP];

    const int tid = threadIdx.x;
    const int lane = tid & 63;
    const int w = tid >> 6;
    const int m16 = lane & 15;
    const int q = lane >> 4;
    const int base = blockIdx.x * R;

    // gather: bufA = [cyc | edge_rep[i0]+edge_rep[i1]]  (bf16)
    {
        const float4* cyc4 = (const float4*)cyc + (size_t)base * 16;
        for (int i = tid; i < R * 16; i += 256) {
            int r = i >> 4, c = i & 15;
            store4bf(&bufA[r * LP + c * 4], cyc4[i]);
        }
        const float4* er4 = (const float4*)edge_rep;
        for (int i = tid; i < R * 16; i += 256) {
            int r = i >> 4, c = i & 15;
            int g = base + r;
            int i0 = e2c[2 * g], i1 = e2c[2 * g + 1];
            float4 a = er4[(size_t)i0 * 16 + c];
            float4 b = er4[(size_t)i1 * 16 + c];
            float4 s{a.x + b.x, a.y + b.y, a.z + b.z, a.w + b.w};
            store4bf(&bufA[r * LP + 64 + c * 4], s);
        }
    }
    __syncthreads();

    layerG<MT, true, 2>(bufA, bufB, W1T, b1, m16, q, w);   // h = relu(in@W1)
    __syncthreads();
    layerG<MT, true, 1>(bufB, bufA, W2T, b2, m16, q, w);   // x -> bufA cols 0:63
    __syncthreads();

    // per-cycle segment sum broadcast into bufA cols 64:127
    {
        int c = tid & 63, grp = tid >> 6;
        for (int cc = grp; cc < C; cc += 4) {
            float s = 0.f;
            #pragma unroll
            for (int j = 0; j < S; ++j) s += bf2f(bufA[(cc * S + j) * LP + c]);
            unsigned short sb = f2bf(s);
            #pragma unroll
            for (int j = 0; j < S; ++j) bufA[(cc * S + j) * LP + 64 + c] = sb;
        }
    }
    __syncthreads();

    layerG<MT, true, 2>(bufA, bufB, WeffT, beff, m16, q, w); // y1
    __syncthreads();
    layerG<MT, true, 2>(bufB, bufA, Wc2T, bc2, m16, q, w);   // y2
    __syncthreads();
    layer_out<MT>(bufA, Wc3T, bc3, out, base, m16, q, w);    // out
}

template<int RB>
__global__ __launch_bounds__(256, 3)
void edge_mfma(const float* __restrict__ edge_rep, const float* __restrict__ cycle_out,
               const int* __restrict__ c2e,
               const unsigned short* __restrict__ We1T, const float* __restrict__ be1,
               const unsigned short* __restrict__ We2T, const float* __restrict__ be2,
               float* __restrict__ out) {
    constexpr int MT = RB / 16;
    __shared__ unsigned short bufA[RB * LP];
    __shared__ unsigned short bufB[RB * LP];

    const int tid = threadIdx.x;
    const int lane = tid & 63;
    const int w = tid >> 6;
    const int m16 = lane & 15;
    const int q = lane >> 4;
    const int base = blockIdx.x * RB;

    {
        const float4* er4 = (const float4*)edge_rep + (size_t)base * 16;
        for (int i = tid; i < RB * 16; i += 256) {
            int r = i >> 4, c = i & 15;
            store4bf(&bufA[r * LP + c * 4], er4[i]);
        }
        const float4* co4 = (const float4*)cycle_out;
        for (int i = tid; i < RB * 16; i += 256) {
            int r = i >> 4, c = i & 15;
            int g = base + r;
            int j0 = c2e[4 * g], j1 = c2e[4 * g + 1], j2 = c2e[4 * g + 2], j3 = c2e[4 * g + 3];
            float4 a = co4[(size_t)j0 * 16 + c];
            float4 b = co4[(size_t)j1 * 16 + c];
            float4 cc = co4[(size_t)j2 * 16 + c];
            float4 d = co4[(size_t)j3 * 16 + c];
            float4 s{a.x + b.x + cc.x + d.x, a.y + b.y + cc.y + d.y,
                     a.z + b.z + cc.z + d.z, a.w + b.w + cc.w + d.w};
            store4bf(&bufA[r * LP + 64 + c * 4], s);
        }
    }
    __syncthreads();

    layerG<MT, true, 2>(bufA, bufB, We1T, be1, m16, q, w);
    __syncthreads();
    layer_out<MT>(bufB, We2T, be2, out, base, m16, q, w);
}

// ---------------- launch ------------------------------------------------------
extern "C" void kernel_launch(void* const* d_in, const int* in_sizes, int n_in,
                              void* d_out, int out_size, void* d_ws, size_t ws_size,
                              hipStream_t stream) {
    const float* edge_rep = (const float*)d_in[0];
    const float* cyc5     = (const float*)d_in[1];
    const float* cyc6     = (const float*)d_in[2];
    const int*   e2c5     = (const int*)  d_in[3];
    const int*   e2c6     = (const int*)  d_in[4];
    const int*   c2e      = (const int*)  d_in[5];
    const float* W1   = (const float*)d_in[6];
    const float* b1   = (const float*)d_in[7];
    const float* W2   = (const float*)d_in[8];
    const float* b2   = (const float*)d_in[9];
    const float* Wc1  = (const float*)d_in[10];
    const float* bc1  = (const float*)d_in[11];
    const float* Wc2  = (const float*)d_in[12];
    const float* bc2  = (const float*)d_in[13];
    const float* Wc3  = (const float*)d_in[14];
    const float* bc3  = (const float*)d_in[15];
    const float* We1  = (const float*)d_in[16];
    const float* be1  = (const float*)d_in[17];
    const float* We2  = (const float*)d_in[18];
    const float* be2  = (const float*)d_in[19];
    const float* Wid5 = (const float*)d_in[20];
    const float* Wsum5= (const float*)d_in[21];
    const float* bab5 = (const float*)d_in[22];
    const float* Wid6 = (const float*)d_in[23];
    const float* Wsum6= (const float*)d_in[24];
    const float* bab6 = (const float*)d_in[25];

    const int NE     = in_sizes[0] / 64;    // 200000
    const int nrows5 = in_sizes[1] / 64;    // 150000
    const int nrows6 = in_sizes[2] / 64;    // 180000

    // workspace layout (bf16 elements)
    unsigned short* wsp    = (unsigned short*)d_ws;
    unsigned short* W1T    = wsp;                 // 128x128
    unsigned short* W2T    = wsp + 16384;         // 64x128
    unsigned short* WeffT5 = wsp + 24576;         // 128x128
    unsigned short* WeffT6 = wsp + 40960;         // 128x128
    unsigned short* Wc2T   = wsp + 57344;         // 128x128
    unsigned short* Wc3T   = wsp + 73728;         // 64x128
    unsigned short* We1T   = wsp + 81920;         // 128x128
    unsigned short* We2T   = wsp + 98304;         // 64x128
    float* beff5 = (float*)(wsp + 106496);        // 128 fp32
    float* beff6 = (float*)(wsp + 106752);        // 128 fp32

    tcast_all<<<288, 256, 0, stream>>>(W1, W2, Wc2, Wc3, We1, We2,
                                       W1T, W2T, Wc2T, Wc3T, We1T, We2T);
    weff_all<<<258, 128, 0, stream>>>(Wc1, Wid5, Wsum5, Wid6, Wsum6,
                                      bab5, bab6, bc1, WeffT5, WeffT6, beff5, beff6);

    float* out      = (float*)d_out;
    float* out5     = out + (size_t)NE * 64;
    float* out6     = out5 + (size_t)nrows5 * 64;
    const float* cycle_out = out5;

    cycle_mfma<5, 16, 3><<<nrows5 / 80, 256, 0, stream>>>(
        edge_rep, cyc5, e2c5, W1T, b1, W2T, b2, WeffT5, beff5,
        Wc2T, bc2, Wc3T, bc3, out5);
    cycle_mfma<6, 8, 4><<<nrows6 / 48, 256, 0, stream>>>(
        edge_rep, cyc6, e2c6, W1T, b1, W2T, b2, WeffT6, beff6,
        Wc2T, bc2, Wc3T, bc3, out6);
    edge_mfma<64><<<NE / 64, 256, 0, stream>>>(
        edge_rep, cycle_out, c2e, We1T, be1, We2T, be2, out);
}